// Round 1
// baseline (5432.363 us; speedup 1.0000x reference)
//
#include <hip/hip_runtime.h>
#include <math.h>

#define N_NODES 100000
#define N_EDGES 2500000
#define N_GRAPHS 512
#define IN_DIM 14
#define HID 32

// tmp[n,o] = sum_k h[n,k] * W[k,o]    (K x 32 weight staged in LDS)
template<int K>
__global__ void gemm_rel(const float* __restrict__ h, const float* __restrict__ W,
                         float* __restrict__ out) {
    __shared__ float sW[K][HID];
    int t = threadIdx.x;
    for (int i = t; i < K * HID; i += 256) sW[i / HID][i % HID] = W[i];
    __syncthreads();
    int idx = blockIdx.x * 256 + t;           // idx = n*32 + o
    if (idx >= N_NODES * HID) return;
    int n = idx >> 5, o = idx & 31;
    const float* hr = h + (long)n * K;
    float acc = 0.f;
#pragma unroll
    for (int k = 0; k < K; ++k) acc += hr[k] * sW[k][o];
    out[idx] = acc;
}

// h_next[n,o] = relu(agg[n,o] + b[o] + sum_k h[n,k] * Wroot[k,o])
template<int K>
__global__ void node_update(const float* __restrict__ h, const float* __restrict__ Wroot,
                            const float* __restrict__ b, const float* __restrict__ agg,
                            float* __restrict__ out) {
    __shared__ float sW[K][HID];
    __shared__ float sb[HID];
    int t = threadIdx.x;
    for (int i = t; i < K * HID; i += 256) sW[i / HID][i % HID] = Wroot[i];
    if (t < HID) sb[t] = b[t];
    __syncthreads();
    int idx = blockIdx.x * 256 + t;           // n*32 + o
    if (idx >= N_NODES * HID) return;
    int n = idx >> 5, o = idx & 31;
    const float* hr = h + (long)n * K;
    float acc = agg[idx] + sb[o];
#pragma unroll
    for (int k = 0; k < K; ++k) acc += hr[k] * sW[k][o];
    out[idx] = fmaxf(acc, 0.f);
}

// agg[dst[e], :] += tmp[src[e], :]   — 8 threads per edge, float4 each
__global__ void scatter32(const int* __restrict__ src, const int* __restrict__ dst,
                          const float* __restrict__ tmp, float* __restrict__ agg) {
    int t = blockIdx.x * 256 + threadIdx.x;
    if (t >= N_EDGES * 8) return;
    int e = t >> 3, q = t & 7;
    int s = src[e], d = dst[e];
    const float4 v = *(const float4*)(tmp + s * HID + q * 4);
    float* a = agg + d * HID + q * 4;
    atomicAdd(a + 0, v.x);
    atomicAdd(a + 1, v.y);
    atomicAdd(a + 2, v.z);
    atomicAdd(a + 3, v.w);
}

// g[batch[n], f] += h[n, f]
__global__ void pool_sum(const float* __restrict__ h, const int* __restrict__ batch,
                         float* __restrict__ g) {
    int idx = blockIdx.x * 256 + threadIdx.x;
    if (idx >= N_NODES * HID) return;
    int n = idx >> 5, f = idx & 31;
    atomicAdd(&g[batch[n] * HID + f], h[idx]);
}

// head: g2 = relu(g@W1 + b1); logits = g2@W2 + b2; out = log_softmax(logits)
__global__ void head(const float* __restrict__ g, const float* __restrict__ w1,
                     const float* __restrict__ b1, const float* __restrict__ w2,
                     const float* __restrict__ b2, float* __restrict__ out) {
    __shared__ float sW1[HID][HID];
    __shared__ float sW2[HID][2];
    __shared__ float sb1[HID];
    int t = threadIdx.x;               // 512 threads, one graph each
    for (int i = t; i < HID * HID; i += 512) sW1[i / HID][i % HID] = w1[i];
    if (t < HID * 2) sW2[t / 2][t % 2] = w2[t];
    if (t < HID) sb1[t] = b1[t];
    __syncthreads();
    float gi[HID];
#pragma unroll
    for (int k = 0; k < HID; ++k) gi[k] = g[t * HID + k];
    float l0 = b2[0], l1 = b2[1];
#pragma unroll
    for (int o = 0; o < HID; ++o) {
        float a = sb1[o];
#pragma unroll
        for (int k = 0; k < HID; ++k) a += gi[k] * sW1[k][o];
        a = fmaxf(a, 0.f);
        l0 += a * sW2[o][0];
        l1 += a * sW2[o][1];
    }
    float m = fmaxf(l0, l1);
    float lse = m + logf(expf(l0 - m) + expf(l1 - m));
    out[t * 2 + 0] = l0 - lse;
    out[t * 2 + 1] = l1 - lse;
}

extern "C" void kernel_launch(void* const* d_in, const int* in_sizes, int n_in,
                              void* d_out, int out_size, void* d_ws, size_t ws_size,
                              hipStream_t stream) {
    const float* x      = (const float*)d_in[0];
    const float* W_rel1 = (const float*)d_in[1];
    const float* b_rel1 = (const float*)d_in[2];
    const float* W_root1= (const float*)d_in[3];
    const float* W_rel  = (const float*)d_in[4];   // 4 x 32 x 32
    const float* b_rel  = (const float*)d_in[5];   // 4 x 32
    const float* W_root = (const float*)d_in[6];   // 4 x 32 x 32
    const float* lin1_w = (const float*)d_in[7];
    const float* lin1_b = (const float*)d_in[8];
    const float* lin2_w = (const float*)d_in[9];
    const float* lin2_b = (const float*)d_in[10];
    const int*   ei     = (const int*)d_in[11];    // [2, E]: src then dst
    const int*   batch  = (const int*)d_in[12];
    float* out = (float*)d_out;

    const int* src = ei;
    const int* dst = ei + N_EDGES;

    float* B0 = (float*)d_ws;                 // N*32
    float* B1 = B0 + (size_t)N_NODES * HID;   // agg, N*32
    float* B2 = B1 + (size_t)N_NODES * HID;   // N*32
    float* g  = B2 + (size_t)N_NODES * HID;   // 512*32

    const int NO = N_NODES * HID;             // 3.2M
    dim3 blk(256);
    dim3 grd_no((NO + 255) / 256);
    dim3 grd_sc((N_EDGES * 8 + 255) / 256);

    // ---- layer 1 (IN_DIM=14 -> 32) ----
    gemm_rel<IN_DIM><<<grd_no, blk, 0, stream>>>(x, W_rel1, B0);
    hipMemsetAsync(B1, 0, (size_t)NO * sizeof(float), stream);
    scatter32<<<grd_sc, blk, 0, stream>>>(src, dst, B0, B1);
    node_update<IN_DIM><<<grd_no, blk, 0, stream>>>(x, W_root1, b_rel1, B1, B2);

    // ---- layers 2..5 (32 -> 32) ----
    float* cur = B2;
    float* tmp = B0;
    for (int i = 0; i < 4; ++i) {
        gemm_rel<HID><<<grd_no, blk, 0, stream>>>(cur, W_rel + i * HID * HID, tmp);
        hipMemsetAsync(B1, 0, (size_t)NO * sizeof(float), stream);
        scatter32<<<grd_sc, blk, 0, stream>>>(src, dst, tmp, B1);
        node_update<HID><<<grd_no, blk, 0, stream>>>(cur, W_root + i * HID * HID,
                                                     b_rel + i * HID, B1, tmp);
        float* nc = tmp; tmp = cur; cur = nc;  // h_next was written into tmp
    }

    // ---- sum pool + head ----
    hipMemsetAsync(g, 0, (size_t)N_GRAPHS * HID * sizeof(float), stream);
    pool_sum<<<grd_no, blk, 0, stream>>>(cur, batch, g);
    head<<<dim3(1), dim3(512), 0, stream>>>(g, lin1_w, lin1_b, lin2_w, lin2_b, out);
}

// Round 2
// 906.242 us; speedup vs baseline: 5.9944x; 5.9944x over previous
//
#include <hip/hip_runtime.h>
#include <math.h>

#define N_NODES 100000
#define N_EDGES 2500000
#define N_GRAPHS 512
#define IN_DIM 14
#define HID 32

// ============ CSR build (by dst) ============

__global__ void histo(const int* __restrict__ dst, int* __restrict__ deg) {
    int e = blockIdx.x * 256 + threadIdx.x;
    if (e < N_EDGES) atomicAdd(&deg[dst[e]], 1);
}

#define SCAN_ITEMS 4
#define SCAN_BLOCK 256
#define SCAN_TILE (SCAN_ITEMS * SCAN_BLOCK)                       // 1024
#define N_SCAN_BLOCKS ((N_NODES + SCAN_TILE - 1) / SCAN_TILE)     // 98

// in-place safe: element i read+written only by its owning thread
__global__ void scan_part(const int* __restrict__ deg, int* __restrict__ rowptr,
                          int* __restrict__ blksum) {
    __shared__ int s[SCAN_BLOCK];
    int t = threadIdx.x;
    int base = blockIdx.x * SCAN_TILE + t * SCAN_ITEMS;
    int v[SCAN_ITEMS];
    int sum = 0;
#pragma unroll
    for (int j = 0; j < SCAN_ITEMS; ++j) {
        int i = base + j;
        v[j] = (i < N_NODES) ? deg[i] : 0;
        sum += v[j];
    }
    s[t] = sum;
    __syncthreads();
    for (int off = 1; off < SCAN_BLOCK; off <<= 1) {
        int x = (t >= off) ? s[t - off] : 0;
        __syncthreads();
        s[t] += x;
        __syncthreads();
    }
    int run = s[t] - sum;  // exclusive prefix for this thread
#pragma unroll
    for (int j = 0; j < SCAN_ITEMS; ++j) {
        int i = base + j;
        if (i < N_NODES) rowptr[i] = run;
        run += v[j];
    }
    if (t == SCAN_BLOCK - 1) blksum[blockIdx.x] = s[t];
}

__global__ void scan_sums(int* __restrict__ blksum) {
    __shared__ int s[SCAN_BLOCK];
    int t = threadIdx.x;
    int v = (t < N_SCAN_BLOCKS) ? blksum[t] : 0;
    s[t] = v;
    __syncthreads();
    for (int off = 1; off < SCAN_BLOCK; off <<= 1) {
        int x = (t >= off) ? s[t - off] : 0;
        __syncthreads();
        s[t] += x;
        __syncthreads();
    }
    if (t < N_SCAN_BLOCKS) blksum[t] = s[t] - v;  // exclusive
}

__global__ void add_off(int* __restrict__ rowptr, const int* __restrict__ blksum,
                        int* __restrict__ cursor) {
    int i = blockIdx.x * 256 + threadIdx.x;
    if (i < N_NODES) {
        int r = rowptr[i] + blksum[i / SCAN_TILE];
        rowptr[i] = r;
        cursor[i] = r;
    }
    if (i == 0) rowptr[N_NODES] = N_EDGES;
}

__global__ void fill_csr(const int* __restrict__ src, const int* __restrict__ dst,
                         int* __restrict__ cursor, int* __restrict__ col) {
    int e = blockIdx.x * 256 + threadIdx.x;
    if (e < N_EDGES) {
        int p = atomicAdd(&cursor[dst[e]], 1);
        col[p] = src[e];
    }
}

// ============ layer-1 pre-GEMM: tmp = x @ W_rel1 (14 -> 32) ============

template <int K>
__global__ void gemm_rel(const float* __restrict__ h, const float* __restrict__ W,
                         float* __restrict__ out) {
    __shared__ float sW[K][HID];
    int t = threadIdx.x;
    for (int i = t; i < K * HID; i += 256) sW[i / HID][i % HID] = W[i];
    __syncthreads();
    int idx = blockIdx.x * 256 + t;  // n*32 + o
    int n = idx >> 5, o = idx & 31;
    const float* hr = h + (long)n * K;
    float acc = 0.f;
#pragma unroll
    for (int k = 0; k < K; ++k) acc += hr[k] * sW[k][o];
    out[idx] = acc;
}

// ============ fused conv: gather + (opt) @Wrel + bias + h@Wroot + relu ============
// 8 lanes per node, each owning a float4 (4 of 32 features).

template <bool MUL_REL, int K>
__global__ void conv_fused(const int* __restrict__ rowptr, const int* __restrict__ col,
                           const float* __restrict__ feat,  // N x 32 gather table
                           const float* __restrict__ hin,   // N x K  root input
                           const float* __restrict__ Wrel,  // 32x32 (if MUL_REL)
                           const float* __restrict__ b,     // 32
                           const float* __restrict__ Wroot, // K x 32
                           float* __restrict__ out) {       // N x 32
    __shared__ float sWrel[HID][HID];
    __shared__ float sWroot[K][HID];
    __shared__ float sb[HID];
    int t = threadIdx.x;
    if (MUL_REL)
        for (int i = t; i < HID * HID; i += 256) sWrel[i >> 5][i & 31] = Wrel[i];
    for (int i = t; i < K * HID; i += 256) sWroot[i / HID][i % HID] = Wroot[i];
    if (t < HID) sb[t] = b[t];
    __syncthreads();

    int n = blockIdx.x * 32 + (t >> 3);  // 3125 blocks * 32 nodes = 100000 exactly
    int q = t & 7;
    int o = q * 4;

    int beg = rowptr[n], end = rowptr[n + 1];
    float4 acc = make_float4(0.f, 0.f, 0.f, 0.f);
    for (int e = beg; e < end; ++e) {
        int c = col[e];
        float4 v = *(const float4*)(feat + c * HID + o);
        acc.x += v.x; acc.y += v.y; acc.z += v.z; acc.w += v.w;
    }

    float r0 = sb[o], r1 = sb[o + 1], r2 = sb[o + 2], r3 = sb[o + 3];
    if constexpr (MUL_REL) {
        float a[4] = {acc.x, acc.y, acc.z, acc.w};
#pragma unroll
        for (int c = 0; c < 8; ++c) {
#pragma unroll
            for (int j = 0; j < 4; ++j) {
                float av = __shfl(a[j], c, 8);
                int k = c * 4 + j;
                r0 += av * sWrel[k][o];
                r1 += av * sWrel[k][o + 1];
                r2 += av * sWrel[k][o + 2];
                r3 += av * sWrel[k][o + 3];
            }
        }
    } else {
        r0 += acc.x; r1 += acc.y; r2 += acc.z; r3 += acc.w;
    }

    if constexpr (K == HID) {
        float4 h4 = *(const float4*)(hin + n * HID + o);
        float hh[4] = {h4.x, h4.y, h4.z, h4.w};
#pragma unroll
        for (int c = 0; c < 8; ++c) {
#pragma unroll
            for (int j = 0; j < 4; ++j) {
                float hv = __shfl(hh[j], c, 8);
                int k = c * 4 + j;
                r0 += hv * sWroot[k][o];
                r1 += hv * sWroot[k][o + 1];
                r2 += hv * sWroot[k][o + 2];
                r3 += hv * sWroot[k][o + 3];
            }
        }
    } else {
        const float* hr = hin + (long)n * K;
#pragma unroll
        for (int k = 0; k < K; ++k) {
            float hv = hr[k];
            r0 += hv * sWroot[k][o];
            r1 += hv * sWroot[k][o + 1];
            r2 += hv * sWroot[k][o + 2];
            r3 += hv * sWroot[k][o + 3];
        }
    }

    float4 res = make_float4(fmaxf(r0, 0.f), fmaxf(r1, 0.f), fmaxf(r2, 0.f), fmaxf(r3, 0.f));
    *(float4*)(out + n * HID + o) = res;
}

// ============ sum pool per graph (batch is sorted -> run-length accumulate) ====

#define POOL_NODES 128  // nodes per block; 8 chunks of 16 per thread-row
__global__ void pool_sum(const float* __restrict__ h, const int* __restrict__ batch,
                         float* __restrict__ g) {
    __shared__ int sbatch[POOL_NODES];
    int t = threadIdx.x;
    int nbase = blockIdx.x * POOL_NODES;
    for (int i = t; i < POOL_NODES; i += 256) {
        int n = nbase + i;
        sbatch[i] = (n < N_NODES) ? batch[n] : -1;
    }
    __syncthreads();
    int f = t & 31;
    int c0 = (t >> 5) * 16;
    int curb = -1;
    float acc = 0.f;
    for (int j = 0; j < 16; ++j) {
        int li = c0 + j;
        int n = nbase + li;
        if (n >= N_NODES) break;
        int bid = sbatch[li];
        float v = h[n * HID + f];
        if (bid != curb) {
            if (curb >= 0) atomicAdd(&g[curb * HID + f], acc);
            curb = bid;
            acc = 0.f;
        }
        acc += v;
    }
    if (curb >= 0) atomicAdd(&g[curb * HID + f], acc);
}

// ============ head: relu(g@W1+b1) @ W2 + b2 -> log_softmax ============

__global__ void head(const float* __restrict__ g, const float* __restrict__ w1,
                     const float* __restrict__ b1, const float* __restrict__ w2,
                     const float* __restrict__ b2, float* __restrict__ out) {
    __shared__ float sW1[HID][HID];
    __shared__ float sW2[HID][2];
    __shared__ float sb1[HID];
    int t = threadIdx.x;  // 512 threads, one graph each
    for (int i = t; i < HID * HID; i += 512) sW1[i / HID][i % HID] = w1[i];
    if (t < HID * 2) sW2[t / 2][t % 2] = w2[t];
    if (t < HID) sb1[t] = b1[t];
    __syncthreads();
    float gi[HID];
#pragma unroll
    for (int k = 0; k < HID; ++k) gi[k] = g[t * HID + k];
    float l0 = b2[0], l1 = b2[1];
#pragma unroll
    for (int o = 0; o < HID; ++o) {
        float a = sb1[o];
#pragma unroll
        for (int k = 0; k < HID; ++k) a += gi[k] * sW1[k][o];
        a = fmaxf(a, 0.f);
        l0 += a * sW2[o][0];
        l1 += a * sW2[o][1];
    }
    float m = fmaxf(l0, l1);
    float lse = m + logf(expf(l0 - m) + expf(l1 - m));
    out[t * 2 + 0] = l0 - lse;
    out[t * 2 + 1] = l1 - lse;
}

extern "C" void kernel_launch(void* const* d_in, const int* in_sizes, int n_in,
                              void* d_out, int out_size, void* d_ws, size_t ws_size,
                              hipStream_t stream) {
    const float* x      = (const float*)d_in[0];
    const float* W_rel1 = (const float*)d_in[1];
    const float* b_rel1 = (const float*)d_in[2];
    const float* W_root1= (const float*)d_in[3];
    const float* W_rel  = (const float*)d_in[4];   // 4 x 32 x 32
    const float* b_rel  = (const float*)d_in[5];   // 4 x 32
    const float* W_root = (const float*)d_in[6];   // 4 x 32 x 32
    const float* lin1_w = (const float*)d_in[7];
    const float* lin1_b = (const float*)d_in[8];
    const float* lin2_w = (const float*)d_in[9];
    const float* lin2_b = (const float*)d_in[10];
    const int*   ei     = (const int*)d_in[11];    // [2, E]: src then dst
    const int*   batch  = (const int*)d_in[12];
    float* out = (float*)d_out;

    const int* src = ei;
    const int* dst = ei + N_EDGES;

    // workspace layout (all 4B types; float4 regions 16B-aligned by construction)
    int*   rowptr = (int*)d_ws;                         // N+1 (doubles as deg), pad to N+8
    int*   cursor = rowptr + N_NODES + 8;               // N
    int*   blksum = cursor + N_NODES;                   // 256
    int*   colarr = blksum + 256;                       // E
    float* B0     = (float*)(colarr + N_EDGES);         // N*32
    float* B1     = B0 + (size_t)N_NODES * HID;         // N*32
    float* g      = B1 + (size_t)N_NODES * HID;         // 512*32

    dim3 blk(256);
    dim3 grd_e((N_EDGES + 255) / 256);        // 9766
    dim3 grd_no((N_NODES * HID + 255) / 256); // 12500
    dim3 grd_cv(N_NODES / 32);                // 3125 (exact)
    dim3 grd_n((N_NODES + 255) / 256);        // 391

    // ---- CSR build ----
    hipMemsetAsync(rowptr, 0, (N_NODES + 1) * sizeof(int), stream);
    histo<<<grd_e, blk, 0, stream>>>(dst, rowptr);
    scan_part<<<dim3(N_SCAN_BLOCKS), blk, 0, stream>>>(rowptr, rowptr, blksum);
    scan_sums<<<dim3(1), blk, 0, stream>>>(blksum);
    add_off<<<grd_n, blk, 0, stream>>>(rowptr, blksum, cursor);
    fill_csr<<<grd_e, blk, 0, stream>>>(src, dst, cursor, colarr);

    // ---- layer 1: tmp = x@W_rel1; h1 = relu(gather(tmp) + b + x@W_root1) ----
    gemm_rel<IN_DIM><<<grd_no, blk, 0, stream>>>(x, W_rel1, B0);
    conv_fused<false, IN_DIM><<<grd_cv, blk, 0, stream>>>(
        rowptr, colarr, B0, x, nullptr, b_rel1, W_root1, B1);

    // ---- layers 2..5: h' = relu(gather(h)@W_rel + b + h@W_root) ----
    float* cur = B1;
    float* nxt = B0;
    for (int i = 0; i < 4; ++i) {
        conv_fused<true, HID><<<grd_cv, blk, 0, stream>>>(
            rowptr, colarr, cur, cur, W_rel + i * HID * HID, b_rel + i * HID,
            W_root + i * HID * HID, nxt);
        float* tswap = cur; cur = nxt; nxt = tswap;
    }
    // final h is in `cur` (B1)

    // ---- sum pool + head ----
    hipMemsetAsync(g, 0, (size_t)N_GRAPHS * HID * sizeof(float), stream);
    pool_sum<<<dim3((N_NODES + POOL_NODES - 1) / POOL_NODES), blk, 0, stream>>>(cur, batch, g);
    head<<<dim3(1), dim3(512), 0, stream>>>(g, lin1_w, lin1_b, lin2_w, lin2_b, out);
}